// Round 1
// baseline (1175.455 us; speedup 1.0000x reference)
//
#include <hip/hip_runtime.h>
#include <cmath>

// Problem constants
#define Bb 256
#define Ss 50
#define Cc 40
#define Dd 256
#define Vv 20000

// ---------------- ws layout (float offsets) ----------------
// WihT   (256x1024)  @ 0
// WhhT   (256x1024)  @ 262144
// WhkT   (256x256)   @ 524288
// W1T    (512x64)    @ 589824
// salpha (256)       @ 622592
// sbeta  (256)       @ 622848
// h0     (256x256)   @ 623104   (zeroed each call)
// cbuf   (256x256)   @ 688640   (zeroed each call)
// gbuf   (256x1024)  @ 754176
// x      (B,S,D)     @ 1016320
// gates  (B,S,4D)    @ 4293120   -- catbuf aliases @4293120 (12544x512),
//                                   tmp aliases @ 4293120+6422528
// rnn    (B,S,D)     @ 17400320  -- aligned aliases here after w GEMM
// w      (B,S,D)     @ 20677120
// H1     (12544x64)  @ 23953920
// attnw  (12544x2)   @ 24756736
// total 24781824 floats = ~99.1 MB
#define OFF_WIHT    0u
#define OFF_WHHT    262144u
#define OFF_WHKT    524288u
#define OFF_W1T     589824u
#define OFF_SALPHA  622592u
#define OFF_SBETA   622848u
#define OFF_H0      623104u
#define OFF_CBUF    688640u
#define OFF_GBUF    754176u
#define OFF_X       1016320u
#define OFF_GATES   4293120u
#define OFF_CAT     4293120u
#define OFF_TMP     (4293120u + 6422528u)
#define OFF_RNN     17400320u
#define OFF_ALIGNED 17400320u
#define OFF_W       20677120u
#define OFF_H1      23953920u
#define OFF_ATTNW   24756736u

// ---------------- generic tiled fp32 GEMM ----------------
// C[M,N] = A[M,K] (row-major, lda) @ Bm[K,N] (row-major, ldb) + bias1 + bias2
// ACT==1: tanh after bias. Grid must exactly tile M,N; K % KT == 0.
template<int BM, int BN, int KT, int TM, int TN, int ACT>
__global__ __launch_bounds__(256) void gemm_kernel(
    const float* __restrict__ A, int lda,
    const float* __restrict__ Bm, int ldb,
    const float* __restrict__ bias1, const float* __restrict__ bias2,
    float* __restrict__ C, int ldc, int K)
{
    constexpr int TX = BN / TN;
    constexpr int TY = BM / TM;
    static_assert(TX * TY == 256, "bad cfg");
    __shared__ float As[KT][BM + 4];
    __shared__ float Bs[KT][BN + 4];
    const int tid = threadIdx.x;
    const int tx = tid % TX;
    const int ty = tid / TX;
    const int m0 = blockIdx.x * BM;
    const int n0 = blockIdx.y * BN;
    float acc[TM][TN];
#pragma unroll
    for (int i = 0; i < TM; ++i)
#pragma unroll
        for (int j = 0; j < TN; ++j) acc[i][j] = 0.f;

    constexpr int A4 = BM * KT / 4;
    constexpr int B4 = KT * BN / 4;
    constexpr int KQ = KT / 4;
    constexpr int CQ = BN / 4;

    for (int k0 = 0; k0 < K; k0 += KT) {
        for (int f = tid; f < A4; f += 256) {
            int r = f / KQ, kq = f % KQ;
            float4 v = *reinterpret_cast<const float4*>(A + (size_t)(m0 + r) * lda + k0 + kq * 4);
            As[kq*4+0][r] = v.x; As[kq*4+1][r] = v.y; As[kq*4+2][r] = v.z; As[kq*4+3][r] = v.w;
        }
        for (int f = tid; f < B4; f += 256) {
            int kk = f / CQ, c4 = f % CQ;
            float4 v = *reinterpret_cast<const float4*>(Bm + (size_t)(k0 + kk) * ldb + n0 + c4 * 4);
            Bs[kk][c4*4+0] = v.x; Bs[kk][c4*4+1] = v.y; Bs[kk][c4*4+2] = v.z; Bs[kk][c4*4+3] = v.w;
        }
        __syncthreads();
#pragma unroll
        for (int kk = 0; kk < KT; ++kk) {
            float a[TM], bb[TN];
#pragma unroll
            for (int i = 0; i < TM; ++i) a[i] = As[kk][ty*TM + i];
#pragma unroll
            for (int j = 0; j < TN; ++j) bb[j] = Bs[kk][tx*TN + j];
#pragma unroll
            for (int i = 0; i < TM; ++i)
#pragma unroll
                for (int j = 0; j < TN; ++j) acc[i][j] += a[i] * bb[j];
        }
        __syncthreads();
    }
#pragma unroll
    for (int i = 0; i < TM; ++i) {
        const int m = m0 + ty * TM + i;
        float* crow = C + (size_t)m * ldc + n0 + tx * TN;
#pragma unroll
        for (int j = 0; j < TN; ++j) {
            float v = acc[i][j];
            const int n = n0 + tx * TN + j;
            if (bias1) v += bias1[n];
            if (bias2) v += bias2[n];
            if (ACT == 1) v = tanhf(v);
            crow[j] = v;
        }
    }
}

// ---------------- transpose: in (R x C) -> out (C x R) ----------------
__global__ __launch_bounds__(256) void transpose_kernel(
    const float* __restrict__ in, float* __restrict__ out, int R, int C)
{
    __shared__ float t[32][33];
    const int c0 = blockIdx.x * 32, r0 = blockIdx.y * 32;
    const int tx = threadIdx.x & 31, ty = threadIdx.x >> 5;  // 32x8
    for (int i = ty; i < 32; i += 8)
        t[i][tx] = in[(size_t)(r0 + i) * C + c0 + tx];
    __syncthreads();
    for (int i = ty; i < 32; i += 8)
        out[(size_t)(c0 + i) * R + r0 + tx] = t[tx][i];
}

// ---------------- per-batch diffusion scale factors ----------------
__global__ void alpha_kernel(const int* __restrict__ tdiff,
                             float* __restrict__ salpha, float* __restrict__ sbeta)
{
    const int b = threadIdx.x;  // 256 threads, 1 block
    const int t = tdiff[b];
    const float step = (0.02f - 1e-4f) / 999.f;
    float prod = 1.f;
    for (int j = 0; j <= t; ++j) prod *= (1.f - (1e-4f + j * step));
    salpha[b] = sqrtf(prod);
    sbeta[b]  = sqrtf(fmaxf(1.f - prod, 0.f));
}

// ---------------- embedding gather-sum ----------------
__global__ __launch_bounds__(256) void embed_kernel(
    const int* __restrict__ seqs, const float* __restrict__ emb, float* __restrict__ x)
{
    __shared__ int idx[Cc];
    const int bs = blockIdx.x;            // b*S+s
    const int tid = threadIdx.x;
    if (tid < Cc) idx[tid] = seqs[(size_t)bs * Cc + tid];
    __syncthreads();
    float s = 0.f;
#pragma unroll 8
    for (int c = 0; c < Cc; ++c) s += emb[(size_t)idx[c] * Dd + tid];
    x[(size_t)bs * Dd + tid] = s;
}

// ---------------- LSTM gate update (after recurrent GEMM) ----------------
__global__ __launch_bounds__(256) void gate_kernel(
    const float* __restrict__ g, const float* __restrict__ gates_pre,
    float* __restrict__ c, float* __restrict__ rnn_out, int t)
{
    const int b = blockIdx.x, d = threadIdx.x;
    const float* gp = gates_pre + ((size_t)b * Ss + t) * (4 * Dd);
    const float* gr = g + (size_t)b * (4 * Dd);
    float gi = gr[d]          + gp[d];
    float gf = gr[Dd + d]     + gp[Dd + d];
    float gg = gr[2*Dd + d]   + gp[2*Dd + d];
    float go = gr[3*Dd + d]   + gp[3*Dd + d];
    float ii = 1.f / (1.f + expf(-gi));
    float ff = 1.f / (1.f + expf(-gf));
    float g2 = tanhf(gg);
    float oo = 1.f / (1.f + expf(-go));
    const size_t ci = (size_t)b * Dd + d;
    float cn = ff * c[ci] + ii * g2;
    c[ci] = cn;
    rnn_out[((size_t)b * Ss + t) * Dd + d] = oo * tanhf(cn);
}

// ---------------- attention: cat build, logits, apply ----------------
__global__ __launch_bounds__(256) void cat_build_kernel(
    const float* __restrict__ x, const float* __restrict__ w, float* __restrict__ cat)
{
    const int r = blockIdx.x;             // b*49+t
    const int b = r / (Ss - 1), t = r % (Ss - 1);
    const int d = threadIdx.x;
    cat[(size_t)r * 512 + d]        = x[((size_t)b * Ss) * Dd + d];
    cat[(size_t)r * 512 + 256 + d]  = w[((size_t)b * Ss + t) * Dd + d];
}

__global__ __launch_bounds__(256) void attn2_kernel(
    const float* __restrict__ H1, const float* __restrict__ W2,
    const float* __restrict__ b2, float* __restrict__ attnw)
{
    const int r = blockIdx.x * 4 + (threadIdx.x >> 6);
    const int j = threadIdx.x & 63;
    float h = H1[(size_t)r * 64 + j];
    float v0 = h * W2[j];
    float v1 = h * W2[64 + j];
#pragma unroll
    for (int off = 32; off; off >>= 1) { v0 += __shfl_down(v0, off); v1 += __shfl_down(v1, off); }
    if (j == 0) {
        float z0 = v0 + b2[0], z1 = v1 + b2[1];
        float m = fmaxf(z0, z1);
        float e0 = expf(z0 - m), e1 = expf(z1 - m);
        float inv = 1.f / (e0 + e1);
        attnw[(size_t)r * 2 + 0] = e0 * inv;
        attnw[(size_t)r * 2 + 1] = e1 * inv;
    }
}

__global__ __launch_bounds__(256) void attn_apply_kernel(
    const float* __restrict__ x, const float* __restrict__ w,
    const float* __restrict__ attnw, float* __restrict__ aligned)
{
    const int bs = blockIdx.x;            // b*S+s
    const int b = bs / Ss, s = bs % Ss;
    const int d = threadIdx.x;
    const float ek = x[((size_t)b * Ss) * Dd + d];
    float v;
    if (s == 0) {
        v = ek;
    } else {
        const int r = b * (Ss - 1) + (s - 1);
        const float a0 = attnw[(size_t)r * 2], a1 = attnw[(size_t)r * 2 + 1];
        v = ek * a0 + w[((size_t)b * Ss + s - 1) * Dd + d] * a1;
    }
    aligned[(size_t)bs * Dd + d] = v;
}

// ---------------- diffusion elementwise ----------------
__global__ __launch_bounds__(256) void diff_kernel(
    const float* __restrict__ aligned, const float* __restrict__ noise,
    const float* __restrict__ temb, const int* __restrict__ tdiff,
    const float* __restrict__ salpha, const float* __restrict__ sbeta,
    float* __restrict__ tmp)
{
    const int bs = blockIdx.x;
    const int b = bs / Ss;
    const int d = threadIdx.x;
    const size_t i = (size_t)bs * Dd + d;
    const int t = tdiff[b];
    tmp[i] = aligned[i] * salpha[b] + noise[i] * sbeta[b] + temb[(size_t)t * Dd + d];
}

// ---------------- pooled 2-class heads ----------------
__device__ inline void pool_reduce_write(float m, const float* __restrict__ Wout,
                                         const float* __restrict__ bout,
                                         float* __restrict__ outp, int b,
                                         float* r0, float* r1)
{
    float v0 = m * Wout[threadIdx.x];
    float v1 = m * Wout[Dd + threadIdx.x];
#pragma unroll
    for (int off = 32; off; off >>= 1) { v0 += __shfl_down(v0, off); v1 += __shfl_down(v1, off); }
    const int lane = threadIdx.x & 63, wv = threadIdx.x >> 6;
    if (lane == 0) { r0[wv] = v0; r1[wv] = v1; }
    __syncthreads();
    if (threadIdx.x == 0) {
        outp[b * 2 + 0] = r0[0] + r0[1] + r0[2] + r0[3] + bout[0];
        outp[b * 2 + 1] = r1[0] + r1[1] + r1[2] + r1[3] + bout[1];
    }
}

__global__ __launch_bounds__(256) void pool_x_kernel(
    const float* __restrict__ x, const float* __restrict__ Wout,
    const float* __restrict__ bout, float* __restrict__ outp)
{
    __shared__ float r0[4], r1[4];
    const int b = blockIdx.x, d = threadIdx.x;
    float m = -INFINITY;
    for (int s = 0; s < Ss; ++s) m = fmaxf(m, x[((size_t)b * Ss + s) * Dd + d]);
    pool_reduce_write(m, Wout, bout, outp, b, r0, r1);
}

__global__ __launch_bounds__(256) void gen_pool_kernel(
    const float* __restrict__ aligned, const float* __restrict__ noise,
    const float* __restrict__ pred, const float* __restrict__ Wout,
    const float* __restrict__ bout, float* __restrict__ outp)
{
    __shared__ float r0[4], r1[4];
    const int b = blockIdx.x, d = threadIdx.x;
    float m = -INFINITY;
    for (int s = 0; s < Ss; ++s) {
        const size_t i = ((size_t)b * Ss + s) * Dd + d;
        m = fmaxf(m, aligned[i] + noise[i] - pred[i]);
    }
    pool_reduce_write(m, Wout, bout, outp, b, r0, r1);
}

// ---------------- host ----------------
extern "C" void kernel_launch(void* const* d_in, const int* in_sizes, int n_in,
                              void* d_out, int out_size, void* d_ws, size_t ws_size,
                              hipStream_t stream)
{
    const int*   seqs  = (const int*)d_in[0];
    const int*   tdiff = (const int*)d_in[5];
    const float* noise = (const float*)d_in[6];
    const float* emb   = (const float*)d_in[7];
    const float* Wih   = (const float*)d_in[8];
    const float* Whh   = (const float*)d_in[9];
    const float* bih   = (const float*)d_in[10];
    const float* bhh   = (const float*)d_in[11];
    const float* Whk   = (const float*)d_in[12];
    const float* bhk   = (const float*)d_in[13];
    const float* W1    = (const float*)d_in[14];
    const float* b1    = (const float*)d_in[15];
    const float* W2    = (const float*)d_in[16];
    const float* b2    = (const float*)d_in[17];
    const float* Wdiff = (const float*)d_in[18];
    const float* bdiff = (const float*)d_in[19];
    const float* temb  = (const float*)d_in[20];
    const float* Wout  = (const float*)d_in[21];
    const float* bout  = (const float*)d_in[22];

    float* outp = (float*)d_out;
    float* ws   = (float*)d_ws;

    float* WihT    = ws + OFF_WIHT;
    float* WhhT    = ws + OFF_WHHT;
    float* WhkT    = ws + OFF_WHKT;
    float* W1T     = ws + OFF_W1T;
    float* salpha  = ws + OFF_SALPHA;
    float* sbeta   = ws + OFF_SBETA;
    float* h0      = ws + OFF_H0;
    float* cbuf    = ws + OFF_CBUF;
    float* gbuf    = ws + OFF_GBUF;
    float* x       = ws + OFF_X;
    float* gates   = ws + OFF_GATES;
    float* catbuf  = ws + OFF_CAT;
    float* tmp     = ws + OFF_TMP;
    float* rnn     = ws + OFF_RNN;
    float* aligned = ws + OFF_ALIGNED;
    float* wbuf    = ws + OFF_W;
    float* H1      = ws + OFF_H1;
    float* attnw   = ws + OFF_ATTNW;

    float* pred_out = outp + 1024;                       // (B,S,D)
    float* noise_out = outp + 1024 + (size_t)Bb*Ss*Dd;   // (B,S,D)

    // zero h0 + cbuf (ws is poisoned each call)
    hipMemsetAsync(h0, 0, (size_t)(2 * Bb * Dd) * sizeof(float), stream);

    alpha_kernel<<<1, 256, 0, stream>>>(tdiff, salpha, sbeta);

    // weight transposes: in (R x C) -> out (C x R); grid (C/32, R/32)
    transpose_kernel<<<dim3(8, 32), 256, 0, stream>>>(Wih, WihT, 1024, 256);
    transpose_kernel<<<dim3(8, 32), 256, 0, stream>>>(Whh, WhhT, 1024, 256);
    transpose_kernel<<<dim3(8, 8),  256, 0, stream>>>(Whk, WhkT, 256, 256);
    transpose_kernel<<<dim3(16, 2), 256, 0, stream>>>(W1,  W1T,  64, 512);

    // x = emb[seqs].sum(axis=2)
    embed_kernel<<<Bb * Ss, 256, 0, stream>>>(seqs, emb, x);

    // pool_x head (only needs x)
    pool_x_kernel<<<Bb, 256, 0, stream>>>(x, Wout, bout, outp);

    // gates_pre = x @ Wih^T + bih + bhh  : (12800 x 1024), K=256
    gemm_kernel<128,128,16,8,8,0><<<dim3(100, 8), 256, 0, stream>>>(
        x, 256, WihT, 1024, bih, bhh, gates, 1024, 256);

    // LSTM recurrence: 50 steps of  g = h_{t-1} @ Whh^T  then gate update
    for (int t = 0; t < Ss; ++t) {
        const float* hprev = (t == 0) ? h0 : (rnn + (size_t)(t - 1) * Dd);
        const int lda = (t == 0) ? Dd : (Ss * Dd);
        gemm_kernel<32,32,32,2,2,0><<<dim3(8, 32), 256, 0, stream>>>(
            hprev, lda, WhhT, 1024, nullptr, nullptr, gbuf, 1024, 256);
        gate_kernel<<<Bb, 256, 0, stream>>>(gbuf, gates, cbuf, rnn, t);
    }

    // w = rnn @ Whk^T + bhk : (12800 x 256), K=256
    gemm_kernel<128,128,16,8,8,0><<<dim3(100, 2), 256, 0, stream>>>(
        rnn, 256, WhkT, 256, bhk, nullptr, wbuf, 256, 256);

    // attention MLP
    cat_build_kernel<<<Bb * (Ss - 1), 256, 0, stream>>>(x, wbuf, catbuf);
    // H1 = tanh(cat @ W1^T + b1) : (12544 x 64), K=512
    gemm_kernel<64,64,16,4,4,1><<<dim3(196, 1), 256, 0, stream>>>(
        catbuf, 512, W1T, 64, b1, nullptr, H1, 64, 512);
    attn2_kernel<<<(Bb * (Ss - 1)) / 4, 256, 0, stream>>>(H1, W2, b2, attnw);
    attn_apply_kernel<<<Bb * Ss, 256, 0, stream>>>(x, wbuf, attnw, aligned);

    // diffusion: tmp = aligned*sqrt(a) + noise*sqrt(1-a) + temb[t]
    diff_kernel<<<Bb * Ss, 256, 0, stream>>>(aligned, noise, temb, tdiff, salpha, sbeta, tmp);

    // predicted_noise = tmp @ Wdiff + bdiff  (Wdiff NOT transposed) -> d_out
    gemm_kernel<128,128,16,8,8,0><<<dim3(100, 2), 256, 0, stream>>>(
        tmp, 256, Wdiff, 256, bdiff, nullptr, pred_out, 256, 256);

    // gen_pool head: max_s(aligned + noise - pred) @ Wout^T + bout
    gen_pool_kernel<<<Bb, 256, 0, stream>>>(aligned, noise, pred_out, Wout, bout, outp + 512);

    // normal_noise passthrough
    hipMemcpyAsync(noise_out, noise, (size_t)Bb * Ss * Dd * sizeof(float),
                   hipMemcpyDeviceToDevice, stream);
}

// Round 2
// 554.902 us; speedup vs baseline: 2.1183x; 2.1183x over previous
//
#include <hip/hip_runtime.h>
#include <cmath>

// Problem constants
#define Bb 256
#define Ss 50
#define Cc 40
#define Dd 256
#define Vv 20000

typedef __bf16 bf16;
typedef __bf16 bf16x8 __attribute__((ext_vector_type(8)));
typedef float f32x4 __attribute__((ext_vector_type(4)));

#define GL2LDS(g, l) __builtin_amdgcn_global_load_lds( \
    (__attribute__((address_space(1))) void*)(g), \
    (__attribute__((address_space(3))) void*)(l), 16, 0, 0)

// ---------------- ws layout (BYTE offsets) ----------------
// gates fp32 (12800x1024)        @ 0          (52,428,800) -- region reused after recurrence:
//    aligned fp32 (12800x256)    @ 0          (13,107,200)
//    cat bf16 (12544x512)        @ 13,107,200 (12,845,056)
//    tmp bf16 (12800x256)        @ 25,952,256 ( 6,553,600)
//    H1 fp32 (12544x64)          @ 32,505,856 ( 3,211,264)
//    attnw fp32 (12544x2)        @ 35,717,120 (   100,352)
// x fp32 (12800x256)             @ 52,428,800 (13,107,200)
// x bf16                         @ 65,536,000 ( 6,553,600)
// rnn bf16 (12800x256)           @ 72,089,600 ( 6,553,600)
// w fp32 (12800x256)             @ 78,643,200 (13,107,200)
// cbuf fp32 (256x256)            @ 91,750,400 (   262,144)
// Wih bf16 (1024x256)            @ 92,012,544 (   524,288)
// Whh bf16 (1024x256)            @ 92,536,832 (   524,288)
// Whk bf16 (256x256)             @ 93,061,120 (   131,072)
// W1  bf16 (64x512)              @ 93,192,192 (    65,536)
// WdiffT bf16 (256x256)          @ 93,257,728 (   131,072)
// salpha fp32 (256)              @ 93,388,800
// sbeta  fp32 (256)              @ 93,389,824
// total ~93.4 MB
#define OFFB_GATES    0ull
#define OFFB_ALIGNED  0ull
#define OFFB_CAT      13107200ull
#define OFFB_TMPB     25952256ull
#define OFFB_H1       32505856ull
#define OFFB_ATTNW    35717120ull
#define OFFB_X        52428800ull
#define OFFB_XB       65536000ull
#define OFFB_RNNB     72089600ull
#define OFFB_W        78643200ull
#define OFFB_CBUF     91750400ull
#define OFFB_WIHB     92012544ull
#define OFFB_WHHB     92536832ull
#define OFFB_WHKB     93061120ull
#define OFFB_W1B      93192192ull
#define OFFB_WDTB     93257728ull
#define OFFB_SALPHA   93388800ull
#define OFFB_SBETA    93389824ull

// ---------------- bf16 MFMA GEMM ----------------
// C[M,N] fp32 = A[M,K] bf16 (row-major, lda) @ B[N,K] bf16 (row-major, ldb)^T
//             + bias1 + bias2; ACT==1 -> tanh.
// Grid exactly tiles (M/BM, N/BN); K % 32 == 0. 256 threads = 4 waves (2x2).
// LDS staged via global_load_lds (16B/lane), XOR-swizzled by (row&3) so
// ds_read_b128 fragment reads are <=2-way bank aliased (free).
template<int BM, int BN, int ACT>
__global__ __launch_bounds__(256) void mfma_gemm(
    const bf16* __restrict__ A, int lda,
    const bf16* __restrict__ B, int ldb,
    const float* __restrict__ bias1, const float* __restrict__ bias2,
    float* __restrict__ C, int ldc, int K)
{
    constexpr int BK = 32;
    constexpr int NF = BN / 32;           // n-frags per wave (2x2 wave grid)
    __shared__ bf16 As[BM * BK];
    __shared__ bf16 Bs[BN * BK];
    const int tid  = threadIdx.x;
    const int wave = tid >> 6;
    const int lane = tid & 63;
    const int m0 = blockIdx.x * BM;
    const int n0 = blockIdx.y * BN;
    const int wm = (wave >> 1) * 64;      // wave row offset in tile
    const int wn = (wave & 1) * (BN / 2); // wave col offset in tile

    f32x4 acc[4][NF];
#pragma unroll
    for (int i = 0; i < 4; ++i)
#pragma unroll
        for (int j = 0; j < NF; ++j) acc[i][j] = (f32x4){0.f, 0.f, 0.f, 0.f};

    const int ar = tid >> 2;              // staging row (0..63) within iter
    const int ac = tid & 3;               // staging chunk
    const int sw = ac ^ (ar & 3);         // swizzled source chunk
    const int lr = lane & 15;
    const int q  = lane >> 4;             // k-chunk of fragment

    for (int k0 = 0; k0 < K; k0 += BK) {
        __syncthreads();
#pragma unroll
        for (int it = 0; it < BM / 64; ++it) {
            const bf16* gp = A + (size_t)(m0 + it * 64 + ar) * lda + k0 + sw * 8;
            GL2LDS(gp, As + it * 2048 + wave * 512);
        }
#pragma unroll
        for (int it = 0; it < BN / 64; ++it) {
            const bf16* gp = B + (size_t)(n0 + it * 64 + ar) * ldb + k0 + sw * 8;
            GL2LDS(gp, Bs + it * 2048 + wave * 512);
        }
        __syncthreads();

        bf16x8 af[4], bfv[NF];
#pragma unroll
        for (int fm = 0; fm < 4; ++fm) {
            int m = wm + fm * 16 + lr;
            af[fm] = *(const bf16x8*)(As + m * 32 + ((q ^ (m & 3)) * 8));
        }
#pragma unroll
        for (int fn = 0; fn < NF; ++fn) {
            int n = wn + fn * 16 + lr;
            bfv[fn] = *(const bf16x8*)(Bs + n * 32 + ((q ^ (n & 3)) * 8));
        }
#pragma unroll
        for (int fm = 0; fm < 4; ++fm)
#pragma unroll
            for (int fn = 0; fn < NF; ++fn)
                acc[fm][fn] = __builtin_amdgcn_mfma_f32_16x16x32_bf16(
                    af[fm], bfv[fn], acc[fm][fn], 0, 0, 0);
    }

    // epilogue: C/D layout col=lane&15, row=(lane>>4)*4+reg
    const int rbase = q * 4;
#pragma unroll
    for (int fn = 0; fn < NF; ++fn) {
        const int col = n0 + wn + fn * 16 + lr;
        float bb = 0.f;
        if (bias1) bb += bias1[col];
        if (bias2) bb += bias2[col];
#pragma unroll
        for (int fm = 0; fm < 4; ++fm) {
            f32x4 v = acc[fm][fn];
#pragma unroll
            for (int r = 0; r < 4; ++r) {
                const int row = m0 + wm + fm * 16 + rbase + r;
                float val = v[r] + bb;
                if (ACT == 1) val = tanhf(val);
                C[(size_t)row * ldc + col] = val;
            }
        }
    }
}

// ---------------- fused LSTM step ----------------
// 256 blocks x 256 threads. Block (bm, bd): batch rows bm*16..+15, hidden cols
// bd*16..+15. Wave g computes gate g's 16x16 recurrent GEMM tile
// (h_{t-1} @ Whh^T) with direct global->register fragments, then all 4 gates
// are exchanged via LDS and the gate update is applied locally.
__global__ __launch_bounds__(256) void lstm_step(
    const bf16* __restrict__ Whhb,    // (1024 x 256) N x K
    const float* __restrict__ gates,  // (B*S x 1024) precomputed x@Wih^T+bih+bhh
    float* __restrict__ cbuf,         // (256 x 256)
    bf16* __restrict__ rnnb,          // (B*S x 256) h outputs
    int t)
{
    __shared__ float gc[4][16][16];
    const int tid  = threadIdx.x;
    const int g    = tid >> 6;        // wave index = gate index
    const int lane = tid & 63;
    const int bm   = blockIdx.x & 15;
    const int bd   = blockIdx.x >> 4;

    f32x4 acc = (f32x4){0.f, 0.f, 0.f, 0.f};
    if (t > 0) {
        const int lr = lane & 15, qq = lane >> 4;
        const bf16* arow = rnnb + ((size_t)(bm * 16 + lr) * Ss + (t - 1)) * Dd + qq * 8;
        const bf16* brow = Whhb + (size_t)(g * 256 + bd * 16 + lr) * Dd + qq * 8;
#pragma unroll
        for (int kc = 0; kc < 8; ++kc) {
            bf16x8 af = *(const bf16x8*)(arow + kc * 32);
            bf16x8 bf = *(const bf16x8*)(brow + kc * 32);
            acc = __builtin_amdgcn_mfma_f32_16x16x32_bf16(af, bf, acc, 0, 0, 0);
        }
    }
    {
        const int lr = lane & 15, rb = (lane >> 4) * 4;
#pragma unroll
        for (int r = 0; r < 4; ++r) gc[g][rb + r][lr] = acc[r];
    }
    __syncthreads();

    const int m  = tid >> 4, d = tid & 15;
    const int b  = bm * 16 + m;
    const int gd = bd * 16 + d;
    const float* gp = gates + ((size_t)b * Ss + t) * 1024;
    float gi = gc[0][m][d] + gp[gd];
    float gf = gc[1][m][d] + gp[256 + gd];
    float gg = gc[2][m][d] + gp[512 + gd];
    float go = gc[3][m][d] + gp[768 + gd];
    float ii = 1.f / (1.f + expf(-gi));
    float ff = 1.f / (1.f + expf(-gf));
    float g2 = tanhf(gg);
    float oo = 1.f / (1.f + expf(-go));
    const size_t ci = (size_t)b * Dd + gd;
    float cprev = (t == 0) ? 0.f : cbuf[ci];
    float cn = ff * cprev + ii * g2;
    cbuf[ci] = cn;
    rnnb[((size_t)b * Ss + t) * Dd + gd] = (bf16)(oo * tanhf(cn));
}

// ---------------- fp32 -> bf16 convert ----------------
__global__ __launch_bounds__(256) void cvt_bf16_kernel(
    const float* __restrict__ src, bf16* __restrict__ dst, int n)
{
    int i = blockIdx.x * 256 + threadIdx.x;
    if (i < n) dst[i] = (bf16)src[i];
}

// transpose + convert: in (R x C) fp32 -> out (C x R) bf16
__global__ __launch_bounds__(256) void transpose_cvt_kernel(
    const float* __restrict__ in, bf16* __restrict__ out, int R, int C)
{
    __shared__ float t[32][33];
    const int c0 = blockIdx.x * 32, r0 = blockIdx.y * 32;
    const int tx = threadIdx.x & 31, ty = threadIdx.x >> 5;  // 32x8
    for (int i = ty; i < 32; i += 8)
        t[i][tx] = in[(size_t)(r0 + i) * C + c0 + tx];
    __syncthreads();
    for (int i = ty; i < 32; i += 8)
        out[(size_t)(c0 + i) * R + r0 + tx] = (bf16)t[tx][i];
}

// ---------------- per-batch diffusion scale factors ----------------
__global__ void alpha_kernel(const int* __restrict__ tdiff,
                             float* __restrict__ salpha, float* __restrict__ sbeta)
{
    const int b = threadIdx.x;
    const int t = tdiff[b];
    const float step = (0.02f - 1e-4f) / 999.f;
    float prod = 1.f;
    for (int j = 0; j <= t; ++j) prod *= (1.f - (1e-4f + j * step));
    salpha[b] = sqrtf(prod);
    sbeta[b]  = sqrtf(fmaxf(1.f - prod, 0.f));
}

// ---------------- embedding gather-sum (fp32 + bf16 outputs) ----------------
__global__ __launch_bounds__(256) void embed_kernel(
    const int* __restrict__ seqs, const float* __restrict__ emb,
    float* __restrict__ x, bf16* __restrict__ xb)
{
    __shared__ int idx[Cc];
    const int bs = blockIdx.x;
    const int tid = threadIdx.x;
    if (tid < Cc) idx[tid] = seqs[(size_t)bs * Cc + tid];
    __syncthreads();
    float s = 0.f;
#pragma unroll 8
    for (int c = 0; c < Cc; ++c) s += emb[(size_t)idx[c] * Dd + tid];
    x[(size_t)bs * Dd + tid]  = s;
    xb[(size_t)bs * Dd + tid] = (bf16)s;
}

// ---------------- attention: cat build (bf16), logits, apply ----------------
__global__ __launch_bounds__(256) void cat_build_kernel(
    const float* __restrict__ x, const float* __restrict__ w, bf16* __restrict__ cat)
{
    const int r = blockIdx.x;             // b*49+t
    const int b = r / (Ss - 1), t = r % (Ss - 1);
    const int d = threadIdx.x;
    cat[(size_t)r * 512 + d]       = (bf16)x[((size_t)b * Ss) * Dd + d];
    cat[(size_t)r * 512 + 256 + d] = (bf16)w[((size_t)b * Ss + t) * Dd + d];
}

__global__ __launch_bounds__(256) void attn2_kernel(
    const float* __restrict__ H1, const float* __restrict__ W2,
    const float* __restrict__ b2, float* __restrict__ attnw)
{
    const int r = blockIdx.x * 4 + (threadIdx.x >> 6);
    const int j = threadIdx.x & 63;
    float h = H1[(size_t)r * 64 + j];
    float v0 = h * W2[j];
    float v1 = h * W2[64 + j];
#pragma unroll
    for (int off = 32; off; off >>= 1) { v0 += __shfl_down(v0, off); v1 += __shfl_down(v1, off); }
    if (j == 0) {
        float z0 = v0 + b2[0], z1 = v1 + b2[1];
        float m = fmaxf(z0, z1);
        float e0 = expf(z0 - m), e1 = expf(z1 - m);
        float inv = 1.f / (e0 + e1);
        attnw[(size_t)r * 2 + 0] = e0 * inv;
        attnw[(size_t)r * 2 + 1] = e1 * inv;
    }
}

__global__ __launch_bounds__(256) void attn_apply_kernel(
    const float* __restrict__ x, const float* __restrict__ w,
    const float* __restrict__ attnw, float* __restrict__ aligned)
{
    const int bs = blockIdx.x;
    const int b = bs / Ss, s = bs % Ss;
    const int d = threadIdx.x;
    const float ek = x[((size_t)b * Ss) * Dd + d];
    float v;
    if (s == 0) {
        v = ek;
    } else {
        const int r = b * (Ss - 1) + (s - 1);
        const float a0 = attnw[(size_t)r * 2], a1 = attnw[(size_t)r * 2 + 1];
        v = ek * a0 + w[((size_t)b * Ss + s - 1) * Dd + d] * a1;
    }
    aligned[(size_t)bs * Dd + d] = v;
}

// ---------------- diffusion elementwise (bf16 output for pred GEMM) ----------
__global__ __launch_bounds__(256) void diff_kernel(
    const float* __restrict__ aligned, const float* __restrict__ noise,
    const float* __restrict__ temb, const int* __restrict__ tdiff,
    const float* __restrict__ salpha, const float* __restrict__ sbeta,
    bf16* __restrict__ tmpb)
{
    const int bs = blockIdx.x;
    const int b = bs / Ss;
    const int d = threadIdx.x;
    const size_t i = (size_t)bs * Dd + d;
    const int t = tdiff[b];
    tmpb[i] = (bf16)(aligned[i] * salpha[b] + noise[i] * sbeta[b] + temb[(size_t)t * Dd + d]);
}

// ---------------- pooled 2-class heads ----------------
__device__ inline void pool_reduce_write(float m, const float* __restrict__ Wout,
                                         const float* __restrict__ bout,
                                         float* __restrict__ outp, int b,
                                         float* r0, float* r1)
{
    float v0 = m * Wout[threadIdx.x];
    float v1 = m * Wout[Dd + threadIdx.x];
#pragma unroll
    for (int off = 32; off; off >>= 1) { v0 += __shfl_down(v0, off); v1 += __shfl_down(v1, off); }
    const int lane = threadIdx.x & 63, wv = threadIdx.x >> 6;
    if (lane == 0) { r0[wv] = v0; r1[wv] = v1; }
    __syncthreads();
    if (threadIdx.x == 0) {
        outp[b * 2 + 0] = r0[0] + r0[1] + r0[2] + r0[3] + bout[0];
        outp[b * 2 + 1] = r1[0] + r1[1] + r1[2] + r1[3] + bout[1];
    }
}

__global__ __launch_bounds__(256) void pool_x_kernel(
    const float* __restrict__ x, const float* __restrict__ Wout,
    const float* __restrict__ bout, float* __restrict__ outp)
{
    __shared__ float r0[4], r1[4];
    const int b = blockIdx.x, d = threadIdx.x;
    float m = -INFINITY;
    for (int s = 0; s < Ss; ++s) m = fmaxf(m, x[((size_t)b * Ss + s) * Dd + d]);
    pool_reduce_write(m, Wout, bout, outp, b, r0, r1);
}

__global__ __launch_bounds__(256) void gen_pool_kernel(
    const float* __restrict__ aligned, const float* __restrict__ noise,
    const float* __restrict__ pred, const float* __restrict__ Wout,
    const float* __restrict__ bout, float* __restrict__ outp)
{
    __shared__ float r0[4], r1[4];
    const int b = blockIdx.x, d = threadIdx.x;
    float m = -INFINITY;
    for (int s = 0; s < Ss; ++s) {
        const size_t i = ((size_t)b * Ss + s) * Dd + d;
        m = fmaxf(m, aligned[i] + noise[i] - pred[i]);
    }
    pool_reduce_write(m, Wout, bout, outp, b, r0, r1);
}

// ---------------- host ----------------
extern "C" void kernel_launch(void* const* d_in, const int* in_sizes, int n_in,
                              void* d_out, int out_size, void* d_ws, size_t ws_size,
                              hipStream_t stream)
{
    const int*   seqs  = (const int*)d_in[0];
    const int*   tdiff = (const int*)d_in[5];
    const float* noise = (const float*)d_in[6];
    const float* emb   = (const float*)d_in[7];
    const float* Wih   = (const float*)d_in[8];
    const float* Whh   = (const float*)d_in[9];
    const float* bih   = (const float*)d_in[10];
    const float* bhh   = (const float*)d_in[11];
    const float* Whk   = (const float*)d_in[12];
    const float* bhk   = (const float*)d_in[13];
    const float* W1    = (const float*)d_in[14];
    const float* b1    = (const float*)d_in[15];
    const float* W2    = (const float*)d_in[16];
    const float* b2    = (const float*)d_in[17];
    const float* Wdiff = (const float*)d_in[18];
    const float* bdiff = (const float*)d_in[19];
    const float* temb  = (const float*)d_in[20];
    const float* Wout  = (const float*)d_in[21];
    const float* bout  = (const float*)d_in[22];

    float* outp = (float*)d_out;
    char*  wsb  = (char*)d_ws;

    float* gates   = (float*)(wsb + OFFB_GATES);
    float* aligned = (float*)(wsb + OFFB_ALIGNED);
    bf16*  catb    = (bf16*) (wsb + OFFB_CAT);
    bf16*  tmpb    = (bf16*) (wsb + OFFB_TMPB);
    float* H1      = (float*)(wsb + OFFB_H1);
    float* attnw   = (float*)(wsb + OFFB_ATTNW);
    float* x       = (float*)(wsb + OFFB_X);
    bf16*  xb      = (bf16*) (wsb + OFFB_XB);
    bf16*  rnnb    = (bf16*) (wsb + OFFB_RNNB);
    float* wbuf    = (float*)(wsb + OFFB_W);
    float* cbuf    = (float*)(wsb + OFFB_CBUF);
    bf16*  Wihb    = (bf16*) (wsb + OFFB_WIHB);
    bf16*  Whhb    = (bf16*) (wsb + OFFB_WHHB);
    bf16*  Whkb    = (bf16*) (wsb + OFFB_WHKB);
    bf16*  W1b     = (bf16*) (wsb + OFFB_W1B);
    bf16*  WdTb    = (bf16*) (wsb + OFFB_WDTB);
    float* salpha  = (float*)(wsb + OFFB_SALPHA);
    float* sbeta   = (float*)(wsb + OFFB_SBETA);

    float* pred_out  = outp + 1024;                        // (B,S,D)
    float* noise_out = outp + 1024 + (size_t)Bb * Ss * Dd; // (B,S,D)

    alpha_kernel<<<1, 256, 0, stream>>>(tdiff, salpha, sbeta);

    // weight converts (weights are already N x K row-major except Wdiff)
    cvt_bf16_kernel<<<1024, 256, 0, stream>>>(Wih, Wihb, 262144);
    cvt_bf16_kernel<<<1024, 256, 0, stream>>>(Whh, Whhb, 262144);
    cvt_bf16_kernel<<<256,  256, 0, stream>>>(Whk, Whkb, 65536);
    cvt_bf16_kernel<<<128,  256, 0, stream>>>(W1,  W1b,  32768);
    transpose_cvt_kernel<<<dim3(8, 8), 256, 0, stream>>>(Wdiff, WdTb, 256, 256);

    // x = emb[seqs].sum(axis=2)  (fp32 + bf16)
    embed_kernel<<<Bb * Ss, 256, 0, stream>>>(seqs, emb, x, xb);

    // pool_x head (only needs x)
    pool_x_kernel<<<Bb, 256, 0, stream>>>(x, Wout, bout, outp);

    // gates_pre = x @ Wih^T + bih + bhh : (12800 x 1024), K=256
    mfma_gemm<128, 128, 0><<<dim3(100, 8), 256, 0, stream>>>(
        xb, 256, Wihb, 256, bih, bhh, gates, 1024, 256);

    // LSTM recurrence: 50 fused steps
    for (int t = 0; t < Ss; ++t)
        lstm_step<<<256, 256, 0, stream>>>(Whhb, gates, cbuf, rnnb, t);

    // w = rnn @ Whk^T + bhk : (12800 x 256), K=256
    mfma_gemm<128, 128, 0><<<dim3(100, 2), 256, 0, stream>>>(
        rnnb, 256, Whkb, 256, bhk, nullptr, wbuf, 256, 256);

    // attention MLP
    cat_build_kernel<<<Bb * (Ss - 1), 256, 0, stream>>>(x, wbuf, catb);
    // H1 = tanh(cat @ W1^T + b1) : (12544 x 64), K=512
    mfma_gemm<128, 64, 1><<<dim3(98, 1), 256, 0, stream>>>(
        catb, 512, W1b, 512, b1, nullptr, H1, 64, 512);
    attn2_kernel<<<(Bb * (Ss - 1)) / 4, 256, 0, stream>>>(H1, W2, b2, attnw);
    attn_apply_kernel<<<Bb * Ss, 256, 0, stream>>>(x, wbuf, attnw, aligned);

    // diffusion: tmp = aligned*sqrt(a) + noise*sqrt(1-a) + temb[t]  (bf16)
    diff_kernel<<<Bb * Ss, 256, 0, stream>>>(aligned, noise, temb, tdiff, salpha, sbeta, tmpb);

    // predicted_noise = tmp @ Wdiff + bdiff -> d_out
    mfma_gemm<128, 128, 0><<<dim3(100, 2), 256, 0, stream>>>(
        tmpb, 256, WdTb, 256, bdiff, nullptr, pred_out, 256, 256);

    // gen_pool head: max_s(aligned + noise - pred) @ Wout^T + bout
    gen_pool_kernel<<<Bb, 256, 0, stream>>>(aligned, noise, pred_out, Wout, bout, outp + 512);

    // normal_noise passthrough
    hipMemcpyAsync(noise_out, noise, (size_t)Bb * Ss * Dd * sizeof(float),
                   hipMemcpyDeviceToDevice, stream);
}